// Round 7
// baseline (315.482 us; speedup 1.0000x reference)
//
#include <hip/hip_runtime.h>
#include <hip/hip_bf16.h>

typedef __attribute__((ext_vector_type(8))) short short8;
typedef __attribute__((ext_vector_type(4))) float f32x4;
typedef unsigned short u16;
typedef unsigned int u32;

#define NBATCH 8
#define NA 1000
#define MD 64
#define GD 50
#define FD 128
#define TOTAL (NBATCH * NA)  // 8000

__device__ __forceinline__ u16 f2bf(float f) {
    u32 x = __float_as_uint(f);
    return (u16)((x + 0x7fffu + ((x >> 16) & 1u)) >> 16);  // RNE
}
__device__ __forceinline__ float bf2f(u16 u) {
    return __uint_as_float(((u32)u) << 16);
}
__device__ __forceinline__ u32 pkbf(float x, float y) {
    __hip_bfloat162 h = __float22bfloat162_rn(float2{x, y});
    return *reinterpret_cast<u32*>(&h);
}
__device__ __forceinline__ float tanh_fast(float x) {
    float e = __expf(2.0f * x);
    return 1.0f - 2.0f * __builtin_amdgcn_rcpf(e + 1.0f);
}
__device__ __forceinline__ f32x4 mfma16(short8 a, short8 b, f32x4 c) {
    return __builtin_amdgcn_mfma_f32_16x16x32_bf16(a, b, c, 0, 0, 0);
}

// ---------------- k0: fp32 weights -> bf16 transposed/padded panels ----------------
// W1T: [128 n][72 k], k<50 valid else 0.
// W2T/WiT: [2 p][128 n][72 kk], k=p*64+kk, kk<64 valid else 0.
__global__ void k0_prep(const float* __restrict__ W1, const float* __restrict__ W2,
                        const float* __restrict__ Wi,
                        u16* __restrict__ W1T, u16* __restrict__ W2T,
                        u16* __restrict__ WiT) {
    const int g0 = blockIdx.x * 256 + threadIdx.x;
    const int gstep = gridDim.x * 256;
    for (int i = g0; i < 128 * 72; i += gstep) {
        int n = i / 72, k = i - n * 72;
        int ks = (k < GD) ? k : 0;
        W1T[i] = (k < GD) ? f2bf(W1[ks * FD + n]) : (u16)0;
    }
    for (int i = g0; i < 2 * 128 * 72; i += gstep) {
        int p = i / 9216;
        int rem = i - p * 9216;
        int n = rem / 72, kk = rem - n * 72;
        bool valid = kk < 64;
        int k = p * 64 + (valid ? kk : 0);
        W2T[i] = valid ? f2bf(W2[k * FD + n]) : (u16)0;
        WiT[i] = valid ? f2bf(Wi[k * FD + n]) : (u16)0;
    }
}

// ---------------- k1: init = features @ W_init -> bf16 in ws ----------------
// W_init fragments in registers (wave owns 2 n-tiles); single barrier.
__global__ __launch_bounds__(256, 3) void k1_init(const float* __restrict__ feat,
                                                  const u16* __restrict__ WiT,
                                                  u16* __restrict__ initB) {
    __shared__ alignas(16) u16 sA[128 * 136];
    const int tid = threadIdx.x, wid = tid >> 6, lane = tid & 63;
    const int quad = lane >> 4, col = lane & 15;
    const int nt0 = 2 * wid;
    const int row0 = blockIdx.x * 128;

    short8 wf[2][4];  // [n][kb]
#pragma unroll
    for (int n = 0; n < 2; ++n)
#pragma unroll
        for (int kb = 0; kb < 4; ++kb)
            wf[n][kb] = *(const short8*)&WiT[(kb >> 1) * 9216 +
                                             ((nt0 + n) * 16 + col) * 72 +
                                             (kb & 1) * 32 + quad * 8];

    for (int i = tid; i < 4096; i += 256) {
        int r = i >> 5, c = (i & 31) * 4;
        int gr = row0 + r;
        float4 v = {0.f, 0.f, 0.f, 0.f};
        if (gr < TOTAL) v = *(const float4*)&feat[(size_t)gr * FD + c];
        u32* p = (u32*)&sA[r * 136 + c];
        p[0] = pkbf(v.x, v.y);
        p[1] = pkbf(v.z, v.w);
    }
    __syncthreads();

    f32x4 acc[8][2];
    const f32x4 zf = {0.f, 0.f, 0.f, 0.f};
#pragma unroll
    for (int m = 0; m < 8; ++m) {
        acc[m][0] = zf;
        acc[m][1] = zf;
    }
#pragma unroll
    for (int kb = 0; kb < 4; ++kb)
#pragma unroll
        for (int m = 0; m < 8; ++m) {
            short8 a = *(const short8*)&sA[(m * 16 + col) * 136 + kb * 32 + quad * 8];
            acc[m][0] = mfma16(a, wf[0][kb], acc[m][0]);
            acc[m][1] = mfma16(a, wf[1][kb], acc[m][1]);
        }
#pragma unroll
    for (int m = 0; m < 8; ++m)
#pragma unroll
        for (int n = 0; n < 2; ++n)
#pragma unroll
            for (int r = 0; r < 4; ++r) {
                int gr = row0 + m * 16 + quad * 4 + r;
                if (gr < TOTAL)
                    initB[(size_t)gr * FD + (nt0 + n) * 16 + col] =
                        f2bf(acc[m][n][r]);
            }
}

// ---------------- k2: fused CFConv + attention + output MLP, 2 atoms / block ----------------
// m-split: wave w owns m-tiles {2w,2w+1} (rows 32w..32w+31), ALL 128 cols.
// LDS 53,760 B -> 3 blocks/CU.
__global__ __launch_bounds__(256, 3) void k2_main(
    const float* __restrict__ rbf, const int* __restrict__ nl,
    const u16* __restrict__ initB,
    const u16* __restrict__ W1T, const u16* __restrict__ W2T,
    const float* __restrict__ b1, const float* __restrict__ b2,
    const float* __restrict__ nbrw,
    const float* __restrict__ Wo1, const float* __restrict__ bo1,
    const float* __restrict__ Wo2, const float* __restrict__ bo2,
    float* __restrict__ outp, float* __restrict__ attnO) {
    __shared__ alignas(16) char smem[53760];
    u16* sA = (u16*)smem;            // [128][72] rbf -> [128][136] H -> [128][136] sInit
    u16* sW = (u16*)(smem + 34816);  // [128][72]: W1 -> W2p0 -> W2p1
    int* nlS = (int*)(smem + 53248);         // [128]; logitS overlays after gather
    float* logitS = (float*)(smem + 53248);  // [128]
    // sW overlays (sW dead after layer-2 B reads):
    float* attnS = (float*)(smem + 34816);         // [128]
    float* aggS = (float*)(smem + 34816 + 512);    // [4][128]
    float* t1S = (float*)(smem + 34816 + 2560);    // [2][128]

    const int tid = threadIdx.x, wid = tid >> 6, lane = tid & 63;
    const int quad = lane >> 4, col = lane & 15;
    const int mt0 = 2 * wid;  // wave's m-tile base (rows 32*wid..)
    const int blk = blockIdx.x;
    const int b = blk / 500;
    const int n0 = (blk - b * 500) * 2;
    const int atom0 = b * NA + n0;
    const size_t rbf_base = (size_t)atom0 * (MD * GD);

    // ---- stage: nl, rbf (fp32->bf16), W1 ----
    if (tid < 128) nlS[tid] = nl[atom0 * MD + tid];
    for (int i = tid; i < 128 * 14; i += 256) {  // zero pad k in [50,64)
        int r = i / 14;
        sA[r * 72 + 50 + (i - r * 14)] = 0;
    }
    for (int i = tid; i < 3200; i += 256) {
        int e = 2 * i;
        int r = e / 50, g = e - r * 50;
        float2 v = *(const float2*)&rbf[rbf_base + e];
        *(u32*)&sA[r * 72 + g] = pkbf(v.x, v.y);
    }
    for (int i = tid; i < 1152; i += 256) ((int4*)sW)[i] = ((const int4*)W1T)[i];
    __syncthreads();  // B1

    // ---- layer 1: rbf @ W1 -> acc1[2 m][8 n] ----
    f32x4 acc1[2][8];
    const f32x4 zf = {0.f, 0.f, 0.f, 0.f};
#pragma unroll
    for (int m = 0; m < 2; ++m)
#pragma unroll
        for (int n = 0; n < 8; ++n) acc1[m][n] = zf;
#pragma unroll
    for (int ks = 0; ks < 2; ++ks) {
        short8 a[2];
#pragma unroll
        for (int m = 0; m < 2; ++m)
            a[m] = *(const short8*)&sA[((mt0 + m) * 16 + col) * 72 + ks * 32 +
                                       quad * 8];
#pragma unroll
        for (int n = 0; n < 8; ++n) {
            short8 bfr = *(const short8*)&sW[(n * 16 + col) * 72 + ks * 32 + quad * 8];
            acc1[0][n] = mfma16(a[0], bfr, acc1[0][n]);
            acc1[1][n] = mfma16(a[1], bfr, acc1[1][n]);
        }
    }
    __syncthreads();  // B2: rbf reads & W1 reads done

    // ---- H = tanh(acc1+b1) -> sA[128][136]; stage W2 panel 0 ----
    float b1v[8];
#pragma unroll
    for (int n = 0; n < 8; ++n) b1v[n] = b1[n * 16 + col];
#pragma unroll
    for (int m = 0; m < 2; ++m)
#pragma unroll
        for (int n = 0; n < 8; ++n)
#pragma unroll
            for (int r = 0; r < 4; ++r) {
                int row = (mt0 + m) * 16 + quad * 4 + r;
                sA[row * 136 + n * 16 + col] =
                    f2bf(tanh_fast(acc1[m][n][r] + b1v[n]));
            }
    for (int i = tid; i < 1152; i += 256) ((int4*)sW)[i] = ((const int4*)W2T)[i];
    __syncthreads();  // B3

    // ---- layer 2: H @ W2 -> acc2[2 m][8 n], two K-panels ----
    f32x4 acc2[2][8];
#pragma unroll
    for (int m = 0; m < 2; ++m)
#pragma unroll
        for (int n = 0; n < 8; ++n) acc2[m][n] = zf;
    for (int half = 0; half < 2; ++half) {
        if (half) {
            __syncthreads();  // B4: panel-0 reads done
            for (int i = tid; i < 1152; i += 256)
                ((int4*)sW)[i] = ((const int4*)(W2T + 9216))[i];
            __syncthreads();  // B5
        }
#pragma unroll
        for (int ks = 0; ks < 2; ++ks) {
            const int ka = half * 64 + ks * 32 + quad * 8;
            const int kb = ks * 32 + quad * 8;
            short8 a[2];
#pragma unroll
            for (int m = 0; m < 2; ++m)
                a[m] = *(const short8*)&sA[((mt0 + m) * 16 + col) * 136 + ka];
#pragma unroll
            for (int n = 0; n < 8; ++n) {
                short8 bfr = *(const short8*)&sW[(n * 16 + col) * 72 + kb];
                acc2[0][n] = mfma16(a[0], bfr, acc2[0][n]);
                acc2[1][n] = mfma16(a[1], bfr, acc2[1][n]);
            }
        }
    }
    __syncthreads();  // B6: all H / W2 reads done

    // ---- gather init rows -> sInit (overlays sA), coalesced dwordx4 ----
    {
        const int lane16 = tid & 15;
        const int rg = tid >> 4;  // 0..15
#pragma unroll
        for (int it = 0; it < 8; ++it) {
            int row = rg + it * 16;
            int nr = b * NA + nlS[row];
            int4 v = *(const int4*)&initB[(size_t)nr * FD + lane16 * 8];
            *(int4*)&sA[row * 136 + lane16 * 8] = v;
        }
    }
    __syncthreads();  // B7

    // ---- conv + logits (wave-local rows) ----
    float b2v[8], wvv[8];
#pragma unroll
    for (int n = 0; n < 8; ++n) {
        b2v[n] = b2[n * 16 + col];
        wvv[n] = nbrw[n * 16 + col];
    }
#pragma unroll
    for (int m = 0; m < 2; ++m)
#pragma unroll
        for (int r = 0; r < 4; ++r) {
            int row = (mt0 + m) * 16 + quad * 4 + r;
            float p = 0.f;
#pragma unroll
            for (int n = 0; n < 8; ++n) {
                float nb = bf2f(sA[row * 136 + n * 16 + col]);
                float cv = (acc2[m][n][r] + b2v[n]) * nb;
                acc2[m][n][r] = cv;  // conv stays in regs
                p += cv * wvv[n];
            }
#pragma unroll
            for (int d = 1; d < 16; d <<= 1) p += __shfl_xor(p, d, 64);
            if (col == 0) logitS[row] = p;  // logitS overlays nlS (nl reads done)
        }
    __syncthreads();  // B8

    // ---- softmax per atom (waves 0,1) ----
    if (wid < 2) {
        float x = logitS[wid * 64 + lane];
        float mx = x;
#pragma unroll
        for (int d = 1; d < 64; d <<= 1) mx = fmaxf(mx, __shfl_xor(mx, d, 64));
        float e = __expf(x - mx);
        float s = e;
#pragma unroll
        for (int d = 1; d < 64; d <<= 1) s += __shfl_xor(s, d, 64);
        float a = e / s;
        attnS[wid * 64 + lane] = a;
        attnO[(size_t)(atom0 + wid) * MD + lane] = a;
    }
    __syncthreads();  // B9

    // ---- agg: wave sums its 32 rows -> aggS[wid][128] ----
    float aggp[8] = {0.f, 0.f, 0.f, 0.f, 0.f, 0.f, 0.f, 0.f};
#pragma unroll
    for (int m = 0; m < 2; ++m)
#pragma unroll
        for (int r = 0; r < 4; ++r) {
            float a = attnS[(mt0 + m) * 16 + quad * 4 + r];
#pragma unroll
            for (int n = 0; n < 8; ++n) aggp[n] += a * acc2[m][n][r];
        }
#pragma unroll
    for (int d = 16; d < 64; d <<= 1)
#pragma unroll
        for (int n = 0; n < 8; ++n) aggp[n] += __shfl_xor(aggp[n], d, 64);
    if (quad == 0) {
#pragma unroll
        for (int n = 0; n < 8; ++n) aggS[wid * 128 + n * 16 + col] = aggp[n];
    }
    __syncthreads();  // B10

    // ---- fused output MLP: out = tanh(agg@Wo1+bo1)@Wo2+bo2 (fp32 weights) ----
    {
        const int a = tid >> 7;   // atom within block
        const int f = tid & 127;  // output feature
        float s = bo1[f];
#pragma unroll 8
        for (int kb = 0; kb < 32; ++kb) {
            float4 u = *(const float4*)&aggS[(2 * a) * 128 + kb * 4];
            float4 v = *(const float4*)&aggS[(2 * a + 1) * 128 + kb * 4];
            const float* wr = &Wo1[(kb * 4) * FD + f];
            s += (u.x + v.x) * wr[0] + (u.y + v.y) * wr[FD] +
                 (u.z + v.z) * wr[2 * FD] + (u.w + v.w) * wr[3 * FD];
        }
        t1S[a * 128 + f] = tanh_fast(s);
        __syncthreads();  // B11
        float o = bo2[f];
#pragma unroll 8
        for (int kb = 0; kb < 32; ++kb) {
            float4 t = *(const float4*)&t1S[a * 128 + kb * 4];
            const float* wr = &Wo2[(kb * 4) * FD + f];
            o += t.x * wr[0] + t.y * wr[FD] + t.z * wr[2 * FD] + t.w * wr[3 * FD];
        }
        outp[(size_t)(atom0 + a) * FD + f] = o;
    }
}

extern "C" void kernel_launch(void* const* d_in, const int* in_sizes, int n_in,
                              void* d_out, int out_size, void* d_ws,
                              size_t ws_size, hipStream_t stream) {
    const float* feat = (const float*)d_in[0];
    const float* rbf  = (const float*)d_in[1];
    const int*   nl   = (const int*)d_in[2];
    const float* Wi   = (const float*)d_in[3];
    const float* W1   = (const float*)d_in[4];
    const float* b1   = (const float*)d_in[5];
    const float* W2   = (const float*)d_in[6];
    const float* b2   = (const float*)d_in[7];
    const float* nbrw = (const float*)d_in[8];
    const float* Wo1  = (const float*)d_in[9];
    const float* bo1  = (const float*)d_in[10];
    const float* Wo2  = (const float*)d_in[11];
    const float* bo2  = (const float*)d_in[12];

    float* outp  = (float*)d_out;               // [8000][128]
    float* attnp = outp + (size_t)TOTAL * FD;   // [8000][64]

    char* ws = (char*)d_ws;                     // total use: ~2.14 MB
    u16* initB = (u16*)ws;                      // 2,048,000 B
    u16* W1T   = (u16*)(ws + 2048000);          // 18,432 B
    u16* W2T   = (u16*)(ws + 2048000 + 18432);  // 36,864 B
    u16* WiT   = (u16*)(ws + 2048000 + 18432 + 36864);  // 36,864 B

    hipLaunchKernelGGL(k0_prep, dim3(40), dim3(256), 0, stream,
                       W1, W2, Wi, W1T, W2T, WiT);
    hipLaunchKernelGGL(k1_init, dim3(63), dim3(256), 0, stream, feat, WiT, initB);
    hipLaunchKernelGGL(k2_main, dim3(4000), dim3(256), 0, stream,
                       rbf, nl, initB, W1T, W2T, b1, b2, nbrw,
                       Wo1, bo1, Wo2, bo2, outp, attnp);
}